// Round 7
// baseline (317.030 us; speedup 1.0000x reference)
//
#include <hip/hip_runtime.h>
#include <hip/hip_bf16.h>
#include <stdint.h>

typedef __bf16 v8bf __attribute__((ext_vector_type(8)));
typedef float f32x4 __attribute__((ext_vector_type(4)));

__device__ __forceinline__ void gload_lds16(const void* g, void* l) {
    __builtin_amdgcn_global_load_lds(
        (const __attribute__((address_space(1))) void*)g,
        (__attribute__((address_space(3))) void*)l, 16, 0, 0);
}

__device__ __forceinline__ unsigned short f2bf(float f) {
    __hip_bfloat16 h = __float2bfloat16(f);
    return __builtin_bit_cast(unsigned short, h);
}

// ---- fused conversion: xc = concat(x,c) bf16 [8][2048][512]; Wbf = 4 weights
__global__ __launch_bounds__(256) void cvt_xcw(const float* __restrict__ x,
                                               const float* __restrict__ c,
                                               const float* __restrict__ wq,
                                               const float* __restrict__ wk,
                                               const float* __restrict__ wv,
                                               const float* __restrict__ wp,
                                               __hip_bfloat16* __restrict__ xc,
                                               __hip_bfloat16* __restrict__ wout) {
    int bid = blockIdx.x;
    if (bid < 8192) {
        int i = bid * 256 + threadIdx.x;
        long e = (long)i * 4;
        int b = (int)(e >> 20);
        int rem = (int)(e & ((1 << 20) - 1));
        int r = rem >> 9;
        int col = rem & 511;
        const float* src = (r < 1024) ? (x + ((long)b << 19) + (long)r * 512 + col)
                                      : (c + ((long)b << 19) + (long)(r - 1024) * 512 + col);
        float4 v = *(const float4*)src;
        ushort4 o;
        o.x = f2bf(v.x); o.y = f2bf(v.y); o.z = f2bf(v.z); o.w = f2bf(v.w);
        ((ushort4*)xc)[i] = o;
    } else {
        int i = (bid - 8192) * 256 + threadIdx.x;
        int e = i * 4;
        int w = e >> 18;
        int off = e & ((1 << 18) - 1);
        const float* src = (w == 0 ? wq : w == 1 ? wk : w == 2 ? wv : wp) + off;
        float4 val = *(const float4*)src;
        ushort4 o;
        o.x = f2bf(val.x); o.y = f2bf(val.y); o.z = f2bf(val.z); o.w = f2bf(val.w);
        ((ushort4*)wout)[i] = o;
    }
}

// mask int32 -> bit-packed uint64 [8][1024][32]; 4 segments per block
__global__ __launch_bounds__(256) void cvt_mask(const int* __restrict__ mask,
                                                unsigned long long* __restrict__ mb) {
    int t = threadIdx.x;
    long base = (long)blockIdx.x * 1024;
#pragma unroll
    for (int j = 0; j < 4; j++) {
        long i = base + j * 256 + t;
        int v = mask[i] != 0;
        unsigned long long bits = __ballot(v);
        if ((t & 63) == 0) mb[i >> 6] = bits;
    }
}

// ---- fused QKV projection GEMM ------------------------------------------
// C[m,n] = sum_k xc[m,k]*Wbf[n,k], M=16384, N=1536. by<8: Q/K head-split
// scatter (Q pre-scaled by 0.125 = softmax scale). by>=8 (V): LDS transpose.
__global__ __launch_bounds__(256) void gemm_qkv(const __hip_bfloat16* __restrict__ A,
                                                const __hip_bfloat16* __restrict__ Bw,
                                                __hip_bfloat16* __restrict__ Qw,
                                                __hip_bfloat16* __restrict__ Kw,
                                                __hip_bfloat16* __restrict__ Vtw) {
    __shared__ union {
        struct { __hip_bfloat16 As[128 * 32]; __hip_bfloat16 Bs[128 * 32]; } s;
        __hip_bfloat16 T[128 * 136];
    } u;
    const int tid = threadIdx.x;
    const int wave = tid >> 6, lane = tid & 63;
    const int m0 = blockIdx.x * 128, n0 = blockIdx.y * 128;

    const int la = lane >> 2;
    const int kc = (lane & 3) * 8;
    const long ga0 = (long)(m0 + wave * 16 + la) * 512 + kc;
    const long ga1 = (long)(m0 + (wave + 4) * 16 + la) * 512 + kc;
    const long gb0 = (long)(n0 + wave * 16 + la) * 512 + kc;
    const long gb1 = (long)(n0 + (wave + 4) * 16 + la) * 512 + kc;

    f32x4 acc[4][4] = {};
    const int mw = (wave & 1) * 64, nw = (wave >> 1) * 64;
    const int lrow = lane & 15, lk = (lane >> 4) * 8;

    for (int k0 = 0; k0 < 512; k0 += 32) {
        gload_lds16(A + ga0 + k0, &u.s.As[wave * 512]);
        gload_lds16(A + ga1 + k0, &u.s.As[(wave + 4) * 512]);
        gload_lds16(Bw + gb0 + k0, &u.s.Bs[wave * 512]);
        gload_lds16(Bw + gb1 + k0, &u.s.Bs[(wave + 4) * 512]);
        __syncthreads();
        v8bf a[4], b[4];
#pragma unroll
        for (int i = 0; i < 4; i++) {
            a[i] = *(const v8bf*)&u.s.As[(mw + i * 16 + lrow) * 32 + lk];
            b[i] = *(const v8bf*)&u.s.Bs[(nw + i * 16 + lrow) * 32 + lk];
        }
#pragma unroll
        for (int mi = 0; mi < 4; mi++)
#pragma unroll
            for (int ni = 0; ni < 4; ni++)
                acc[mi][ni] = __builtin_amdgcn_mfma_f32_16x16x32_bf16(a[mi], b[ni], acc[mi][ni], 0, 0, 0);
        __syncthreads();
    }

    const int lq = lane >> 4;
    if (blockIdx.y < 8) {
#pragma unroll
        for (int mi = 0; mi < 4; mi++)
#pragma unroll
            for (int ni = 0; ni < 4; ni++)
#pragma unroll
                for (int r = 0; r < 4; r++) {
                    int grow = m0 + mw + mi * 16 + lq * 4 + r;
                    int gcol = n0 + nw + ni * 16 + lrow;
                    int w = gcol >> 9, g9 = gcol & 511;
                    int h = g9 >> 6, dh = g9 & 63;
                    int b_ = grow >> 11, rr = grow & 2047;
                    float val = acc[mi][ni][r];
                    if (w == 0) {
                        if (rr < 1024)
                            Qw[((long)(b_ * 8 + h) * 1024 + rr) * 64 + dh] =
                                __float2bfloat16(val * 0.125f);   // fold softmax scale
                    } else {
                        Kw[((long)(b_ * 8 + h) * 2048 + rr) * 64 + dh] = __float2bfloat16(val);
                    }
                }
    } else {
#pragma unroll
        for (int mi = 0; mi < 4; mi++)
#pragma unroll
            for (int ni = 0; ni < 4; ni++) {
                int n_l = nw + ni * 16 + lrow;
                int m_l = mw + mi * 16 + lq * 4;
                ushort4 pk;
                pk.x = f2bf(acc[mi][ni][0]); pk.y = f2bf(acc[mi][ni][1]);
                pk.z = f2bf(acc[mi][ni][2]); pk.w = f2bf(acc[mi][ni][3]);
                *(ushort4*)&u.T[n_l * 136 + m_l] = pk;
            }
        __syncthreads();
        const int no = (blockIdx.y - 8) * 128;
        const int b_ = m0 >> 11, rrb = m0 & 2047;
#pragma unroll
        for (int i = 0; i < 8; i++) {
            int s = tid + i * 256;
            int n_l = s >> 4, ch = s & 15;
            int ng = no + n_l;
            int h = ng >> 6, dh = ng & 63;
            uint4 v = *(const uint4*)&u.T[n_l * 136 + ch * 8];
            *(uint4*)&Vtw[((long)(b_ * 8 + h) * 64 + dh) * 2048 + rrb + ch * 8] = v;
        }
    }
}

// ---- output projection GEMM: d_out[m,n] = sum_k Yb[m,k]*Wp[n,k], fp32 out
__global__ __launch_bounds__(256) void gemm_out(const __hip_bfloat16* __restrict__ A,
                                                const __hip_bfloat16* __restrict__ Bw,
                                                float* __restrict__ outp) {
    __shared__ __hip_bfloat16 As[128 * 32];
    __shared__ __hip_bfloat16 Bs[128 * 32];
    const int tid = threadIdx.x;
    const int wave = tid >> 6, lane = tid & 63;
    const int m0 = blockIdx.x * 128, n0 = blockIdx.y * 128;

    const int la = lane >> 2;
    const int kc = (lane & 3) * 8;
    const long ga0 = (long)(m0 + wave * 16 + la) * 512 + kc;
    const long ga1 = (long)(m0 + (wave + 4) * 16 + la) * 512 + kc;
    const long gb0 = (long)(n0 + wave * 16 + la) * 512 + kc;
    const long gb1 = (long)(n0 + (wave + 4) * 16 + la) * 512 + kc;

    f32x4 acc[4][4] = {};
    const int mw = (wave & 1) * 64, nw = (wave >> 1) * 64;
    const int lrow = lane & 15, lk = (lane >> 4) * 8;

    for (int k0 = 0; k0 < 512; k0 += 32) {
        gload_lds16(A + ga0 + k0, &As[wave * 512]);
        gload_lds16(A + ga1 + k0, &As[(wave + 4) * 512]);
        gload_lds16(Bw + gb0 + k0, &Bs[wave * 512]);
        gload_lds16(Bw + gb1 + k0, &Bs[(wave + 4) * 512]);
        __syncthreads();
        v8bf a[4], b[4];
#pragma unroll
        for (int i = 0; i < 4; i++) {
            a[i] = *(const v8bf*)&As[(mw + i * 16 + lrow) * 32 + lk];
            b[i] = *(const v8bf*)&Bs[(nw + i * 16 + lrow) * 32 + lk];
        }
#pragma unroll
        for (int mi = 0; mi < 4; mi++)
#pragma unroll
            for (int ni = 0; ni < 4; ni++)
                acc[mi][ni] = __builtin_amdgcn_mfma_f32_16x16x32_bf16(a[mi], b[ni], acc[mi][ni], 0, 0, 0);
        __syncthreads();
    }

    const int lq = lane >> 4;
#pragma unroll
    for (int mi = 0; mi < 4; mi++)
#pragma unroll
        for (int ni = 0; ni < 4; ni++)
#pragma unroll
            for (int r = 0; r < 4; r++) {
                int grow = m0 + mw + mi * 16 + lq * 4 + r;
                int gcol = n0 + nw + ni * 16 + lrow;
                outp[(long)grow * 512 + gcol] = acc[mi][ni][r];
            }
}

// ---- flash attention v3: key-split S-phase, d-split PV phase -------------
// grid 1024 (b=L&7 XCD-pinned). Block 4 waves, 64 q, 128 keys/iter.
// S: wave w computes S^T for keys {kt2*64 + w*16 + [0,16)} (K frags direct
// from global), exp+mask, writes P to shared LDS [64q][128k] (XOR-swizzled).
// PV: wave w owns d-slice w*16+[0,16) for ALL q -> Oacc = 4 f32x4 (16 AGPR).
// No cross-wave O reduction; only lsum is summed across waves at the end.
__global__ __launch_bounds__(256) void flash(const __hip_bfloat16* __restrict__ Q,
                                             const __hip_bfloat16* __restrict__ K,
                                             const __hip_bfloat16* __restrict__ Vt,
                                             const unsigned long long* __restrict__ Mb,
                                             __hip_bfloat16* __restrict__ Y) {
    __shared__ __hip_bfloat16 Ps[64 * 128];   // [q][key], 16B chunks XOR (q&7)
    __shared__ float Ls[4][64];               // per-wave partial row sums

    const int L = blockIdx.x;
    const int b = L & 7, h = L >> 7, qt = (L >> 3) & 15;
    const int bh = b * 8 + h;
    const int tid = threadIdx.x, w = tid >> 6, lane = tid & 63;
    const int lcol = lane & 15, lq = lane >> 4;

    const __hip_bfloat16* Qp = Q + ((long)bh * 1024 + qt * 64) * 64;
    const __hip_bfloat16* Kp = K + ((long)bh * 2048 + w * 16 + lcol) * 64;   // S A-frag rows
    const __hip_bfloat16* Vp = Vt + ((long)bh * 64 + w * 16 + lcol) * 2048;  // PV B-frag rows
    const unsigned long long* Mp = Mb + ((long)b * 1024 + qt * 64) * 32;

    // Q B-frags (all 64 q), register-resident; Q pre-scaled by 0.125
    v8bf bq[4][2];
#pragma unroll
    for (int mi = 0; mi < 4; mi++)
#pragma unroll
        for (int ks = 0; ks < 2; ks++)
            bq[mi][ks] = *(const v8bf*)(Qp + (mi * 16 + lcol) * 64 + ks * 32 + lq * 8);

    f32x4 Oacc[4] = {};
    float lsum[4] = {0.f, 0.f, 0.f, 0.f};
    const int mshift = w * 16 + lq * 4;

    for (int kt = 0; kt < 16; kt++) {
        // mask words + K A-frags for this wave's 32 keys
        unsigned long long mb_[4][2];
#pragma unroll
        for (int mi = 0; mi < 4; mi++)
#pragma unroll
            for (int kt2 = 0; kt2 < 2; kt2++)
                mb_[mi][kt2] = Mp[(mi * 16 + lcol) * 32 + kt * 2 + kt2] >> mshift;

        v8bf ak[2][2];
#pragma unroll
        for (int kt2 = 0; kt2 < 2; kt2++)
#pragma unroll
            for (int ks = 0; ks < 2; ks++)
                ak[kt2][ks] = *(const v8bf*)(Kp + (long)(kt * 128 + kt2 * 64) * 64 + ks * 32 + lq * 8);

        // S^T = K Q^T; exp; P -> shared LDS
#pragma unroll
        for (int kt2 = 0; kt2 < 2; kt2++)
#pragma unroll
            for (int mi = 0; mi < 4; mi++) {
                f32x4 st = {};
                st = __builtin_amdgcn_mfma_f32_16x16x32_bf16(ak[kt2][0], bq[mi][0], st, 0, 0, 0);
                st = __builtin_amdgcn_mfma_f32_16x16x32_bf16(ak[kt2][1], bq[mi][1], st, 0, 0, 0);
                ushort4 pk;
#pragma unroll
                for (int r = 0; r < 4; r++) {
                    float s = fminf(st[r], 40.f);
                    float e = __expf(s);
                    e = ((mb_[mi][kt2] >> r) & 1ull) ? 0.f : e;
                    lsum[mi] += e;
                    ((unsigned short*)&pk)[r] = f2bf(e);
                }
                int q = mi * 16 + lcol;
                int ch = (kt2 * 8 + w * 2 + (lq >> 1)) ^ (q & 7);
                *(ushort4*)((char*)Ps + q * 256 + ch * 16 + (lq & 1) * 8) = pk;
            }

        // V B-frags for PV (independent of LDS; latency hides under barrier)
        v8bf bv[4];
#pragma unroll
        for (int kc = 0; kc < 4; kc++)
            bv[kc] = *(const v8bf*)(Vp + kt * 128 + kc * 32 + lq * 8);

        __syncthreads();

        // PV: wave w's d-slice over all 64 q, K=32 per MFMA
#pragma unroll
        for (int mi = 0; mi < 4; mi++) {
            int q = mi * 16 + lcol;
#pragma unroll
            for (int kc = 0; kc < 4; kc++) {
                v8bf ap = *(const v8bf*)((char*)Ps + q * 256 + (((kc * 4 + lq) ^ (q & 7)) * 16));
                Oacc[mi] = __builtin_amdgcn_mfma_f32_16x16x32_bf16(ap, bv[kc], Oacc[mi], 0, 0, 0);
            }
        }
        __syncthreads();
    }

    // lsum: reduce over lq groups, publish per-wave partials
#pragma unroll
    for (int mi = 0; mi < 4; mi++) {
        float s = lsum[mi];
        s += __shfl_xor(s, 16);
        s += __shfl_xor(s, 32);
        lsum[mi] = s;
    }
    if (lq == 0) {
#pragma unroll
        for (int mi = 0; mi < 4; mi++) Ls[w][mi * 16 + lcol] = lsum[mi];
    }
    __syncthreads();

    // epilogue: wave stores its own d-slice; rows from C-layout (q = lq*4+r)
#pragma unroll
    for (int mi = 0; mi < 4; mi++) {
#pragma unroll
        for (int r = 0; r < 4; r++) {
            int q = mi * 16 + lq * 4 + r;
            float rs = Ls[0][q] + Ls[1][q] + Ls[2][q] + Ls[3][q];
            float inv = 1.f / rs;
            long row = (long)b * 1024 + qt * 64 + q;
            Y[row * 512 + h * 64 + w * 16 + lcol] = __float2bfloat16(Oacc[mi][r] * inv);
        }
    }
}

// ---- launch -------------------------------------------------------------
extern "C" void kernel_launch(void* const* d_in, const int* in_sizes, int n_in,
                              void* d_out, int out_size, void* d_ws, size_t ws_size,
                              hipStream_t stream) {
    const float* x = (const float*)d_in[0];
    const float* c = (const float*)d_in[1];
    const int* mask = (const int*)d_in[2];
    const float* Wq = (const float*)d_in[3];
    const float* Wk = (const float*)d_in[4];
    const float* Wv = (const float*)d_in[5];
    const float* Wp = (const float*)d_in[6];

    char* ws = (char*)d_ws;
    __hip_bfloat16* xc  = (__hip_bfloat16*)(ws);                 // 16 MB (dead after gemm_qkv)
    __hip_bfloat16* Wbf = (__hip_bfloat16*)(ws + 16777216);      //  2 MB
    __hip_bfloat16* Qw  = (__hip_bfloat16*)(ws + 18874368);      //  8 MB
    __hip_bfloat16* Kw  = (__hip_bfloat16*)(ws + 27262976);      // 16 MB
    __hip_bfloat16* Vtw = (__hip_bfloat16*)(ws + 44040192);      // 16 MB
    __hip_bfloat16* Yb  = (__hip_bfloat16*)(ws + 60817408);      //  8 MB
    unsigned long long* Mbp = (unsigned long long*)(ws);         //  2 MB, aliases dead xc

    cvt_xcw<<<9216, 256, 0, stream>>>(x, c, Wq, Wk, Wv, Wp, xc, Wbf);
    gemm_qkv<<<dim3(128, 12), 256, 0, stream>>>(xc, Wbf, Qw, Kw, Vtw);
    cvt_mask<<<16384, 256, 0, stream>>>(mask, Mbp);   // after gemm_qkv: overwrites xc
    flash<<<1024, 256, 0, stream>>>(Qw, Kw, Vtw, Mbp, Yb);
    gemm_out<<<dim3(64, 4), 256, 0, stream>>>(Yb, Wbf + 3 * 262144, (float*)d_out);
}